// Round 15
// baseline (84.755 us; speedup 1.0000x reference)
//
#include <hip/hip_runtime.h>
#include <stdint.h>
#include <math.h>

#define WAVE 64
#define TOPK 16

// Monotone bijection fp32 -> uint32 (order-preserving).
__device__ __forceinline__ uint32_t f2s(float f) {
    uint32_t u = __float_as_uint(f);
    return u ^ (uint32_t)(((int32_t)u >> 31) | 0x80000000u);
}
__device__ __forceinline__ uint32_t umax32(uint32_t a, uint32_t b) { return a > b ? a : b; }
__device__ __forceinline__ uint32_t umin32(uint32_t a, uint32_t b) { return a < b ? a : b; }

template <int CTRL, int RMASK>
__device__ __forceinline__ uint32_t dppmax(uint32_t m) {
    uint32_t r = (uint32_t)__builtin_amdgcn_update_dpp((int)m, (int)m, CTRL, RMASK, 0xF, false);
    return umax32(m, r);
}
// Wave-wide (64-lane) max, pure VALU (DPP) + one readlane. Returns uniform value.
__device__ __forceinline__ uint32_t wave_umax(uint32_t m) {
    m = dppmax<0x121, 0xF>(m);  // row_ror:1
    m = dppmax<0x122, 0xF>(m);  // row_ror:2
    m = dppmax<0x124, 0xF>(m);  // row_ror:4
    m = dppmax<0x128, 0xF>(m);  // row_ror:8  -> row max everywhere
    m = dppmax<0x142, 0xA>(m);  // row_bcast:15 -> rows 1,3
    m = dppmax<0x143, 0xC>(m);  // row_bcast:31 -> rows 2,3; lane 63 = global
    return (uint32_t)__builtin_amdgcn_readlane((int)m, 63);
}

template <int VPL>
__device__ __forceinline__ uint32_t gpos(int j, int lane) {
    if constexpr (VPL == 1) return (uint32_t)lane;
    else return (uint32_t)((j >> 2) * (WAVE * 4) + lane * 4 + (j & 3));
}

#define CE_(x, y) { const uint32_t h_ = umax32(x, y), l_ = umin32(x, y); (x) = h_; (y) = l_; }

// ---------- generic top-16 selection (R4-verbatim) for P=64/256 ----------
template <int P>
__device__ __forceinline__ void topk_select(const float* __restrict__ crow,
                                            const int lane,
                                            uint32_t* __restrict__ idx) {
    constexpr int VPL = P / WAVE;
    constexpr uint32_t IMASK = (uint32_t)(P - 1);

    uint32_t k[VPL];
    if constexpr (VPL == 1) {
        k[0] = (f2s(crow[lane]) & ~IMASK) | (uint32_t)lane;
    } else {
#pragma unroll
        for (int c = 0; c < VPL / 4; ++c) {
            float4 f4 = *reinterpret_cast<const float4*>(crow + c * (WAVE * 4) + lane * 4);
            const uint32_t b = (uint32_t)(c * (WAVE * 4) + lane * 4);
            k[c * 4 + 0] = (f2s(f4.x) & ~IMASK) | (b + 0u);
            k[c * 4 + 1] = (f2s(f4.y) & ~IMASK) | (b + 1u);
            k[c * 4 + 2] = (f2s(f4.z) & ~IMASK) | (b + 2u);
            k[c * 4 + 3] = (f2s(f4.w) & ~IMASK) | (b + 3u);
        }
#pragma unroll
        for (int size = 2; size <= VPL; size <<= 1) {
#pragma unroll
            for (int stride = size >> 1; stride > 0; stride >>= 1) {
#pragma unroll
                for (int i = 0; i < VPL; ++i) {
                    const int j = i ^ stride;
                    if (j > i) {
                        if ((i & size) == 0) { CE_(k[i], k[j]); }
                        else                 { CE_(k[j], k[i]); }
                    }
                }
            }
        }
    }

    uint32_t q16 = 0;
#pragma unroll
    for (int t = 0; t < TOPK; ++t) {
        const uint32_t K = wave_umax(k[0]);
        idx[t] = K & IMASK;
        if (t == TOPK - 1) q16 = K & ~IMASK;
        const bool won = (k[0] == K);
#pragma unroll
        for (int j = 0; j < VPL - 1; ++j) k[j] = won ? k[j + 1] : k[j];
        k[VPL - 1] = won ? 0u : k[VPL - 1];
    }
    const uint32_t k17 = wave_umax(k[0]);

    if ((k17 & ~IMASK) == q16) {
        // EXACT fallback (rare): lexicographic (value, index) iterative extract.
        uint32_t v[VPL];
        if constexpr (VPL == 1) {
            v[0] = f2s(crow[lane]);
        } else {
#pragma unroll
            for (int c = 0; c < VPL / 4; ++c) {
                float4 f4 = *reinterpret_cast<const float4*>(crow + c * (WAVE * 4) + lane * 4);
                v[c * 4 + 0] = f2s(f4.x);
                v[c * 4 + 1] = f2s(f4.y);
                v[c * 4 + 2] = f2s(f4.z);
                v[c * 4 + 3] = f2s(f4.w);
            }
        }
#pragma unroll
        for (int t = 0; t < TOPK; ++t) {
            uint32_t m = v[0];
            int li = 0;
#pragma unroll
            for (int j = 1; j < VPL; ++j) {
                bool c = v[j] >= m;
                m = c ? v[j] : m;
                li = c ? j : li;
            }
            uint32_t gi = gpos<VPL>(li, lane);
            const uint32_t mygi = gi;
            uint32_t mm = m;
#pragma unroll
            for (int off = 32; off > 0; off >>= 1) {
                uint32_t om = (uint32_t)__shfl_xor((int)mm, off);
                uint32_t og = (uint32_t)__shfl_xor((int)gi, off);
                bool c = (om > mm) || (om == mm && og > gi);
                mm = c ? om : mm;
                gi = c ? og : gi;
            }
            idx[t] = gi;
            const bool won = (mygi == gi) && (m == mm);
#pragma unroll
            for (int j = 0; j < VPL; ++j) {
                if (won && j == li) v[j] = 0u;
            }
        }
    }
}

// ---------- specialized P=1024: top-4 sorted head + 12-entry reserve ----------
// (R11-validated) Winner sequence identical to full-sort version.
__device__ __forceinline__ void topk_select_1024(const float* __restrict__ crow,
                                                 const int lane,
                                                 uint32_t* __restrict__ idx) {
    constexpr uint32_t IMASK = 1023u;

    uint32_t k[16];
#pragma unroll
    for (int c = 0; c < 4; ++c) {
        float4 f4 = *reinterpret_cast<const float4*>(crow + c * (WAVE * 4) + lane * 4);
        const uint32_t b = (uint32_t)(c * (WAVE * 4) + lane * 4);
        k[c * 4 + 0] = (f2s(f4.x) & ~IMASK) | (b + 0u);
        k[c * 4 + 1] = (f2s(f4.y) & ~IMASK) | (b + 1u);
        k[c * 4 + 2] = (f2s(f4.z) & ~IMASK) | (b + 2u);
        k[c * 4 + 3] = (f2s(f4.w) & ~IMASK) | (b + 3u);
    }
#pragma unroll
    for (int c = 0; c < 4; ++c) {
        CE_(k[4 * c + 0], k[4 * c + 1]); CE_(k[4 * c + 2], k[4 * c + 3]);
        CE_(k[4 * c + 0], k[4 * c + 2]); CE_(k[4 * c + 1], k[4 * c + 3]);
        CE_(k[4 * c + 1], k[4 * c + 2]);
    }
    uint32_t h[4], g[4], t[4], r[12];
#pragma unroll
    for (int i = 0; i < 4; ++i) { h[i] = umax32(k[i], k[7 - i]); r[i] = umin32(k[i], k[7 - i]); }
    CE_(h[0], h[2]); CE_(h[1], h[3]); CE_(h[0], h[1]); CE_(h[2], h[3]);
#pragma unroll
    for (int i = 0; i < 4; ++i) { g[i] = umax32(k[8 + i], k[15 - i]); r[4 + i] = umin32(k[8 + i], k[15 - i]); }
    CE_(g[0], g[2]); CE_(g[1], g[3]); CE_(g[0], g[1]); CE_(g[2], g[3]);
#pragma unroll
    for (int i = 0; i < 4; ++i) { t[i] = umax32(h[i], g[3 - i]); r[8 + i] = umin32(h[i], g[3 - i]); }
    CE_(t[0], t[2]); CE_(t[1], t[3]); CE_(t[0], t[1]); CE_(t[2], t[3]);

    uint32_t q16 = 0;
#pragma unroll
    for (int tt = 0; tt < TOPK; ++tt) {
        if (__any(t[0] == 0u)) {
            const bool need = (t[0] == 0u);
            uint32_t rm = r[0];
#pragma unroll
            for (int j = 1; j < 12; ++j) rm = umax32(rm, r[j]);
#pragma unroll
            for (int j = 0; j < 12; ++j) r[j] = (need && r[j] == rm) ? 0u : r[j];
            t[0] = need ? rm : t[0];
        }
        const uint32_t K = wave_umax(t[0]);
        idx[tt] = K & IMASK;
        if (tt == TOPK - 1) q16 = K & ~IMASK;
        const bool won = (t[0] == K);
        t[0] = won ? t[1] : t[0];
        t[1] = won ? t[2] : t[1];
        t[2] = won ? t[3] : t[2];
        t[3] = won ? 0u : t[3];
    }
    if (__any(t[0] == 0u)) {
        const bool need = (t[0] == 0u);
        uint32_t rm = r[0];
#pragma unroll
        for (int j = 1; j < 12; ++j) rm = umax32(rm, r[j]);
        t[0] = need ? rm : t[0];
    }
    const uint32_t k17 = wave_umax(t[0]);

    if ((k17 & ~IMASK) == q16) {
        uint32_t v[16];
#pragma unroll
        for (int c = 0; c < 4; ++c) {
            float4 f4 = *reinterpret_cast<const float4*>(crow + c * (WAVE * 4) + lane * 4);
            v[c * 4 + 0] = f2s(f4.x);
            v[c * 4 + 1] = f2s(f4.y);
            v[c * 4 + 2] = f2s(f4.z);
            v[c * 4 + 3] = f2s(f4.w);
        }
#pragma unroll
        for (int tt = 0; tt < TOPK; ++tt) {
            uint32_t m = v[0];
            int li = 0;
#pragma unroll
            for (int j = 1; j < 16; ++j) {
                bool c = v[j] >= m;
                m = c ? v[j] : m;
                li = c ? j : li;
            }
            uint32_t gi = gpos<16>(li, lane);
            const uint32_t mygi = gi;
            uint32_t mm = m;
#pragma unroll
            for (int off = 32; off > 0; off >>= 1) {
                uint32_t om = (uint32_t)__shfl_xor((int)mm, off);
                uint32_t og = (uint32_t)__shfl_xor((int)gi, off);
                bool c = (om > mm) || (om == mm && og > gi);
                mm = c ? om : mm;
                gi = c ? og : gi;
            }
            idx[tt] = gi;
            const bool won = (mygi == gi) && (m == mm);
#pragma unroll
            for (int j = 0; j < 16; ++j) {
                if (won && j == li) v[j] = 0u;
            }
        }
    }
}

// ---------- fused k1+k2 in ONE kernel: e2 lives in LDS, __syncthreads ----------
// 64 blocks x 1024 threads (16 waves). Phase 1: each block redundantly computes
// all 256 e2 rows into LDS (16 rows/wave, ~2us, parallel across blocks).
// Phase 2: each wave does one conn2 row (block covers 16 of the 1024 rows),
// gathering e2 from LDS (wave-uniform row -> lane-consecutive, conflict-free).
#define F12_BLOCKS 64

__global__ void __launch_bounds__(1024)
fused12_lds(const float* __restrict__ conn2,
            const float* __restrict__ conn3,
            const float* __restrict__ root,
            float* __restrict__ e1) {
    __shared__ float e2s[256 * 64];  // 64 KB
    const int lane = threadIdx.x & (WAVE - 1);
    const int wib = threadIdx.x >> 6;  // 0..15

    // Phase 1: e2 rows (R4-verbatim math; parent = root)
    for (int r = wib; r < 256; r += 16) {
        const float* __restrict__ c3 = conn3 + r * 64;
        uint32_t idx[TOPK];
        topk_select<64>(c3, lane, idx);
        float vsel[TOPK];
#pragma unroll
        for (int t = 0; t < TOPK; ++t) vsel[t] = c3[idx[t]];
        const float v0 = vsel[0];
        float ssum = 0.f, acc = 0.f;
#pragma unroll
        for (int t = 0; t < TOPK; ++t) {
            const float w = __expf(vsel[t] - v0);
            ssum += w;
            acc = fmaf(w, root[idx[t] * 64u + (uint32_t)lane], acc);
        }
        e2s[r * 64 + lane] = acc / ssum;
    }
    __syncthreads();

    // Phase 2: one conn2 row per wave
    const int row = blockIdx.x * 16 + wib;  // 0..1023
    const float* __restrict__ crow = conn2 + (long)row * 256;
    uint32_t idx[TOPK];
    topk_select<256>(crow, lane, idx);
    float vsel[TOPK];
#pragma unroll
    for (int t = 0; t < TOPK; ++t) vsel[t] = crow[idx[t]];
    const float v0 = vsel[0];
    float ssum = 0.f, acc = 0.f;
#pragma unroll
    for (int t = 0; t < TOPK; ++t) {
        const float w = __expf(vsel[t] - v0);
        ssum += w;
        acc = fmaf(w, e2s[idx[t] * 64u + (uint32_t)lane], acc);
    }
    e1[(long)row * 64 + lane] = acc / ssum;
}

// ---------- leaves (k3): R11-verbatim ----------
__global__ void leaf_kernel(const int* __restrict__ ids,
                            const float* __restrict__ conn1,
                            const float* __restrict__ e1,
                            float* __restrict__ out,
                            int batch) {
    const int lane = threadIdx.x & (WAVE - 1);
    const int row = blockIdx.x * (blockDim.x >> 6) + (threadIdx.x >> 6);
    if (row >= batch) return;

    const float* __restrict__ crow = conn1 + (long)ids[row] * 1024;

    uint32_t idx[TOPK];
    topk_select_1024(crow, lane, idx);

    float vsel[TOPK];
#pragma unroll
    for (int t = 0; t < TOPK; ++t) vsel[t] = crow[idx[t]];
    const float v0 = vsel[0];
    float ssum = 0.f, acc = 0.f;
#pragma unroll
    for (int t = 0; t < TOPK; ++t) {
        const float w = __expf(vsel[t] - v0);
        ssum += w;
        acc = fmaf(w, e1[idx[t] * 64u + (uint32_t)lane], acc);
    }
    out[(long)row * 64 + lane] = acc / ssum;
}

extern "C" void kernel_launch(void* const* d_in, const int* in_sizes, int n_in,
                              void* d_out, int out_size, void* d_ws, size_t ws_size,
                              hipStream_t stream) {
    const int* ids = (const int*)d_in[0];          // [8192] int32
    const float* conn1 = (const float*)d_in[1];    // [200000, 1024]
    const float* conn2 = (const float*)d_in[2];    // [1024, 256]
    const float* conn3 = (const float*)d_in[3];    // [256, 64]
    const float* root = (const float*)d_in[4];     // [64, 64]
    float* out = (float*)d_out;                    // [8192, 64]

    const int batch = in_sizes[0];                 // 8192

    float* e1 = (float*)d_ws;                      // [1024, 64]

    // Node 1: fused levels 2+1 (e2 in LDS, __syncthreads dependency)
    fused12_lds<<<dim3(F12_BLOCKS), dim3(1024), 0, stream>>>(conn2, conn3, root, e1);

    // Node 2: leaves (R11-verbatim)
    leaf_kernel<<<dim3(batch / 4), dim3(256), 0, stream>>>(ids, conn1, e1, out, batch);
}

// Round 16
// 32.750 us; speedup vs baseline: 2.5879x; 2.5879x over previous
//
#include <hip/hip_runtime.h>
#include <stdint.h>
#include <math.h>

#define WAVE 64
#define TOPK 16

// Monotone bijection fp32 -> uint32 (order-preserving).
__device__ __forceinline__ uint32_t f2s(float f) {
    uint32_t u = __float_as_uint(f);
    return u ^ (uint32_t)(((int32_t)u >> 31) | 0x80000000u);
}
__device__ __forceinline__ uint32_t umax32(uint32_t a, uint32_t b) { return a > b ? a : b; }
__device__ __forceinline__ uint32_t umin32(uint32_t a, uint32_t b) { return a < b ? a : b; }

template <int CTRL, int RMASK>
__device__ __forceinline__ uint32_t dppmax(uint32_t m) {
    uint32_t r = (uint32_t)__builtin_amdgcn_update_dpp((int)m, (int)m, CTRL, RMASK, 0xF, false);
    return umax32(m, r);
}
// Wave-wide (64-lane) max, pure VALU (DPP) + one readlane. Returns uniform value.
__device__ __forceinline__ uint32_t wave_umax(uint32_t m) {
    m = dppmax<0x121, 0xF>(m);  // row_ror:1
    m = dppmax<0x122, 0xF>(m);  // row_ror:2
    m = dppmax<0x124, 0xF>(m);  // row_ror:4
    m = dppmax<0x128, 0xF>(m);  // row_ror:8  -> row max everywhere
    m = dppmax<0x142, 0xA>(m);  // row_bcast:15 -> rows 1,3
    m = dppmax<0x143, 0xC>(m);  // row_bcast:31 -> rows 2,3; lane 63 = global
    return (uint32_t)__builtin_amdgcn_readlane((int)m, 63);
}

template <int VPL>
__device__ __forceinline__ uint32_t gpos(int j, int lane) {
    if constexpr (VPL == 1) return (uint32_t)lane;
    else return (uint32_t)((j >> 2) * (WAVE * 4) + lane * 4 + (j & 3));
}

#define CE_(x, y) { const uint32_t h_ = umax32(x, y), l_ = umin32(x, y); (x) = h_; (y) = l_; }

// ---------- generic top-16 selection (R4-verbatim) for P=64/256 ----------
template <int P>
__device__ __forceinline__ void topk_select(const float* __restrict__ crow,
                                            const int lane,
                                            uint32_t* __restrict__ idx) {
    constexpr int VPL = P / WAVE;
    constexpr uint32_t IMASK = (uint32_t)(P - 1);

    uint32_t k[VPL];
    if constexpr (VPL == 1) {
        k[0] = (f2s(crow[lane]) & ~IMASK) | (uint32_t)lane;
    } else {
#pragma unroll
        for (int c = 0; c < VPL / 4; ++c) {
            float4 f4 = *reinterpret_cast<const float4*>(crow + c * (WAVE * 4) + lane * 4);
            const uint32_t b = (uint32_t)(c * (WAVE * 4) + lane * 4);
            k[c * 4 + 0] = (f2s(f4.x) & ~IMASK) | (b + 0u);
            k[c * 4 + 1] = (f2s(f4.y) & ~IMASK) | (b + 1u);
            k[c * 4 + 2] = (f2s(f4.z) & ~IMASK) | (b + 2u);
            k[c * 4 + 3] = (f2s(f4.w) & ~IMASK) | (b + 3u);
        }
#pragma unroll
        for (int size = 2; size <= VPL; size <<= 1) {
#pragma unroll
            for (int stride = size >> 1; stride > 0; stride >>= 1) {
#pragma unroll
                for (int i = 0; i < VPL; ++i) {
                    const int j = i ^ stride;
                    if (j > i) {
                        if ((i & size) == 0) { CE_(k[i], k[j]); }
                        else                 { CE_(k[j], k[i]); }
                    }
                }
            }
        }
    }

    uint32_t q16 = 0;
#pragma unroll
    for (int t = 0; t < TOPK; ++t) {
        const uint32_t K = wave_umax(k[0]);
        idx[t] = K & IMASK;
        if (t == TOPK - 1) q16 = K & ~IMASK;
        const bool won = (k[0] == K);
#pragma unroll
        for (int j = 0; j < VPL - 1; ++j) k[j] = won ? k[j + 1] : k[j];
        k[VPL - 1] = won ? 0u : k[VPL - 1];
    }
    const uint32_t k17 = wave_umax(k[0]);

    if ((k17 & ~IMASK) == q16) {
        // EXACT fallback (rare): lexicographic (value, index) iterative extract.
        uint32_t v[VPL];
        if constexpr (VPL == 1) {
            v[0] = f2s(crow[lane]);
        } else {
#pragma unroll
            for (int c = 0; c < VPL / 4; ++c) {
                float4 f4 = *reinterpret_cast<const float4*>(crow + c * (WAVE * 4) + lane * 4);
                v[c * 4 + 0] = f2s(f4.x);
                v[c * 4 + 1] = f2s(f4.y);
                v[c * 4 + 2] = f2s(f4.z);
                v[c * 4 + 3] = f2s(f4.w);
            }
        }
#pragma unroll
        for (int t = 0; t < TOPK; ++t) {
            uint32_t m = v[0];
            int li = 0;
#pragma unroll
            for (int j = 1; j < VPL; ++j) {
                bool c = v[j] >= m;
                m = c ? v[j] : m;
                li = c ? j : li;
            }
            uint32_t gi = gpos<VPL>(li, lane);
            const uint32_t mygi = gi;
            uint32_t mm = m;
#pragma unroll
            for (int off = 32; off > 0; off >>= 1) {
                uint32_t om = (uint32_t)__shfl_xor((int)mm, off);
                uint32_t og = (uint32_t)__shfl_xor((int)gi, off);
                bool c = (om > mm) || (om == mm && og > gi);
                mm = c ? om : mm;
                gi = c ? og : gi;
            }
            idx[t] = gi;
            const bool won = (mygi == gi) && (m == mm);
#pragma unroll
            for (int j = 0; j < VPL; ++j) {
                if (won && j == li) v[j] = 0u;
            }
        }
    }
}

// ---------- specialized P=1024: top-4 sorted head + 12-entry reserve ----------
// (R11-validated) Winner sequence identical to full-sort version.
__device__ __forceinline__ void topk_select_1024(const float* __restrict__ crow,
                                                 const int lane,
                                                 uint32_t* __restrict__ idx) {
    constexpr uint32_t IMASK = 1023u;

    uint32_t k[16];
#pragma unroll
    for (int c = 0; c < 4; ++c) {
        float4 f4 = *reinterpret_cast<const float4*>(crow + c * (WAVE * 4) + lane * 4);
        const uint32_t b = (uint32_t)(c * (WAVE * 4) + lane * 4);
        k[c * 4 + 0] = (f2s(f4.x) & ~IMASK) | (b + 0u);
        k[c * 4 + 1] = (f2s(f4.y) & ~IMASK) | (b + 1u);
        k[c * 4 + 2] = (f2s(f4.z) & ~IMASK) | (b + 2u);
        k[c * 4 + 3] = (f2s(f4.w) & ~IMASK) | (b + 3u);
    }
    // sort each quad desc (5 CE each)
#pragma unroll
    for (int c = 0; c < 4; ++c) {
        CE_(k[4 * c + 0], k[4 * c + 1]); CE_(k[4 * c + 2], k[4 * c + 3]);
        CE_(k[4 * c + 0], k[4 * c + 2]); CE_(k[4 * c + 1], k[4 * c + 3]);
        CE_(k[4 * c + 1], k[4 * c + 2]);
    }
    uint32_t h[4], g[4], t[4], r[12];
#pragma unroll
    for (int i = 0; i < 4; ++i) { h[i] = umax32(k[i], k[7 - i]); r[i] = umin32(k[i], k[7 - i]); }
    CE_(h[0], h[2]); CE_(h[1], h[3]); CE_(h[0], h[1]); CE_(h[2], h[3]);
#pragma unroll
    for (int i = 0; i < 4; ++i) { g[i] = umax32(k[8 + i], k[15 - i]); r[4 + i] = umin32(k[8 + i], k[15 - i]); }
    CE_(g[0], g[2]); CE_(g[1], g[3]); CE_(g[0], g[1]); CE_(g[2], g[3]);
#pragma unroll
    for (int i = 0; i < 4; ++i) { t[i] = umax32(h[i], g[3 - i]); r[8 + i] = umin32(h[i], g[3 - i]); }
    CE_(t[0], t[2]); CE_(t[1], t[3]); CE_(t[0], t[1]); CE_(t[2], t[3]);

    uint32_t q16 = 0;
#pragma unroll
    for (int tt = 0; tt < TOPK; ++tt) {
        if (__any(t[0] == 0u)) {
            const bool need = (t[0] == 0u);
            uint32_t rm = r[0];
#pragma unroll
            for (int j = 1; j < 12; ++j) rm = umax32(rm, r[j]);
#pragma unroll
            for (int j = 0; j < 12; ++j) r[j] = (need && r[j] == rm) ? 0u : r[j];
            t[0] = need ? rm : t[0];
        }
        const uint32_t K = wave_umax(t[0]);
        idx[tt] = K & IMASK;
        if (tt == TOPK - 1) q16 = K & ~IMASK;
        const bool won = (t[0] == K);
        t[0] = won ? t[1] : t[0];
        t[1] = won ? t[2] : t[1];
        t[2] = won ? t[3] : t[2];
        t[3] = won ? 0u : t[3];
    }
    if (__any(t[0] == 0u)) {
        const bool need = (t[0] == 0u);
        uint32_t rm = r[0];
#pragma unroll
        for (int j = 1; j < 12; ++j) rm = umax32(rm, r[j]);
        t[0] = need ? rm : t[0];
    }
    const uint32_t k17 = wave_umax(t[0]);

    if ((k17 & ~IMASK) == q16) {
        // EXACT fallback (rare): lexicographic (value, index) iterative extract.
        uint32_t v[16];
#pragma unroll
        for (int c = 0; c < 4; ++c) {
            float4 f4 = *reinterpret_cast<const float4*>(crow + c * (WAVE * 4) + lane * 4);
            v[c * 4 + 0] = f2s(f4.x);
            v[c * 4 + 1] = f2s(f4.y);
            v[c * 4 + 2] = f2s(f4.z);
            v[c * 4 + 3] = f2s(f4.w);
        }
#pragma unroll
        for (int tt = 0; tt < TOPK; ++tt) {
            uint32_t m = v[0];
            int li = 0;
#pragma unroll
            for (int j = 1; j < 16; ++j) {
                bool c = v[j] >= m;
                m = c ? v[j] : m;
                li = c ? j : li;
            }
            uint32_t gi = gpos<16>(li, lane);
            const uint32_t mygi = gi;
            uint32_t mm = m;
#pragma unroll
            for (int off = 32; off > 0; off >>= 1) {
                uint32_t om = (uint32_t)__shfl_xor((int)mm, off);
                uint32_t og = (uint32_t)__shfl_xor((int)gi, off);
                bool c = (om > mm) || (om == mm && og > gi);
                mm = c ? om : mm;
                gi = c ? og : gi;
            }
            idx[tt] = gi;
            const bool won = (mygi == gi) && (m == mm);
#pragma unroll
            for (int j = 0; j < 16; ++j) {
                if (won && j == li) v[j] = 0u;
            }
        }
    }
}

// ---------- inner levels (k1, k2): one wave per row ----------
template <int P>
__global__ void topk_wm_kernel(const float* __restrict__ conn,
                               const float* __restrict__ parent,
                               float* __restrict__ out,
                               int n) {
    const int lane = threadIdx.x & (WAVE - 1);
    const int row = blockIdx.x * (blockDim.x >> 6) + (threadIdx.x >> 6);
    if (row >= n) return;

    const float* __restrict__ crow = conn + (long)row * P;

    uint32_t idx[TOPK];
    topk_select<P>(crow, lane, idx);

    float vsel[TOPK];
#pragma unroll
    for (int t = 0; t < TOPK; ++t) vsel[t] = crow[idx[t]];
    const float v0 = vsel[0];
    float ssum = 0.f, acc = 0.f;
#pragma unroll
    for (int t = 0; t < TOPK; ++t) {
        const float w = __expf(vsel[t] - v0);
        ssum += w;
        acc = fmaf(w, parent[idx[t] * 64u + (uint32_t)lane], acc);
    }
    out[(long)row * 64 + lane] = acc / ssum;
}

// ---------- leaves (k3): one wave per row ----------
__global__ void leaf_kernel(const int* __restrict__ ids,
                            const float* __restrict__ conn1,
                            const float* __restrict__ e1,
                            float* __restrict__ out,
                            int batch) {
    const int lane = threadIdx.x & (WAVE - 1);
    const int row = blockIdx.x * (blockDim.x >> 6) + (threadIdx.x >> 6);
    if (row >= batch) return;

    const float* __restrict__ crow = conn1 + (long)ids[row] * 1024;

    uint32_t idx[TOPK];
    topk_select_1024(crow, lane, idx);

    float vsel[TOPK];
#pragma unroll
    for (int t = 0; t < TOPK; ++t) vsel[t] = crow[idx[t]];
    const float v0 = vsel[0];
    float ssum = 0.f, acc = 0.f;
#pragma unroll
    for (int t = 0; t < TOPK; ++t) {
        const float w = __expf(vsel[t] - v0);
        ssum += w;
        acc = fmaf(w, e1[idx[t] * 64u + (uint32_t)lane], acc);
    }
    out[(long)row * 64 + lane] = acc / ssum;
}

extern "C" void kernel_launch(void* const* d_in, const int* in_sizes, int n_in,
                              void* d_out, int out_size, void* d_ws, size_t ws_size,
                              hipStream_t stream) {
    const int* ids = (const int*)d_in[0];          // [8192] int32
    const float* conn1 = (const float*)d_in[1];    // [200000, 1024]
    const float* conn2 = (const float*)d_in[2];    // [1024, 256]
    const float* conn3 = (const float*)d_in[3];    // [256, 64]
    const float* root = (const float*)d_in[4];     // [64, 64]
    float* out = (float*)d_out;                    // [8192, 64]

    const int batch = in_sizes[0];                 // 8192
    const int n1 = 1024, n2 = 256;

    float* e2 = (float*)d_ws;                      // [256, 64]
    float* e1 = e2 + (size_t)n2 * 64;              // [1024, 64]

    // Level 2: 256 rows, one wave per block (max CU spread for latency)
    topk_wm_kernel<64><<<dim3(n2), dim3(64), 0, stream>>>(conn3, root, e2, n2);

    // Level 1: 1024 rows, 4 waves/block
    topk_wm_kernel<256><<<dim3(n1 / 4), dim3(256), 0, stream>>>(conn2, e2, e1, n1);

    // Leaves: 8192 rows, 4 waves/block
    leaf_kernel<<<dim3(batch / 4), dim3(256), 0, stream>>>(conn1 == nullptr ? nullptr : ids, conn1, e1, out, batch);
}